// Round 9
// baseline (522.964 us; speedup 1.0000x reference)
//
#include <hip/hip_runtime.h>

// LSTM: HIDDEN=128, SEQ=7, BATCH=65536. fp32 in/out.
// fp16 MFMA GEMM per timestep, c state in registers, h staged via LDS,
// double-buffered, 1 barrier/timestep.
//
// R2-R5: spill fixes + BT=32 dbuf single-barrier. 544->200us.
// R6: pure-fp16 h (absmax floor is harness-side). 153us.
// R7: fused-reciprocal epilogue. 147us. VALUBusy 55% @ 2 waves/SIMD.
// R8: persistent-B: VGPR 148 -> 1 wave/SIMD -> 207us. REGRESSION, but
//     proves throughput ~ resident waves (latency-bound, not L2-bound).
// R9: BT=16 halves per-thread state (acc 16, c_r 8) -> fits 128-reg total
//     under launch_bounds(256,4) -> 4 waves/SIMD. Grid 4096. Also fold
//     log2e into packed weights: __expf(mul+exp) -> exp2f (bare v_exp).

#define SEQ 7
#define BT 16
#define L2E 1.442695041f  // log2(e)

typedef _Float16 half8 __attribute__((ext_vector_type(8)));
typedef float floatx4 __attribute__((ext_vector_type(4)));

__device__ __forceinline__ floatx4 mfma16(half8 a, half8 b, floatx4 c) {
  return __builtin_amdgcn_mfma_f32_16x16x32_f16(a, b, c, 0, 0, 0);
}

// Pack W_hh [512][128] fp32 into fragment-major fp16, PRE-SCALED by
// log2e (gates i,f,o) or 2*log2e (gate g) so the epilogue uses bare exp2.
// B-operand layout for mfma_f32_16x16x32_f16: lane = kq*16 + col holds
// B[k = kq*8 + jj][n = col] for the 16-col tile.
__global__ void pack_kernel(const float* __restrict__ Whh,
                            _Float16* __restrict__ Bp) {
  int idx = blockIdx.x * 256 + threadIdx.x;   // 0..65535 = j*128 + k
  int j = idx >> 7, k = idx & 127;
  int g = j >> 7;                             // gate group 0..3 (i,f,g,o)
  float sc = (g == 2) ? 2.0f * L2E : L2E;
  _Float16 hi = (_Float16)(Whh[idx] * sc);
  int nt = j >> 4, col = j & 15;              // 16-col N-tile, col within
  int kk = k >> 5, r = k & 31;                // 32-K step, k within
  int kq = r >> 3, jj = r & 7;
  int base = (((nt << 2) + kk) * 64 + (kq << 4) + col) * 8 + jj;
  Bp[base] = hi;
}

__launch_bounds__(256, 4)
__global__ void lstm_kernel(const float* __restrict__ x,
                            const float* __restrict__ x0,
                            const float* __restrict__ Wih,
                            const float* __restrict__ bih,
                            const float* __restrict__ bhh,
                            const float* __restrict__ Wout,
                            const float* __restrict__ boutp,
                            const _Float16* __restrict__ Bp,
                            float* __restrict__ out) {
  // h staged as fp16, double-buffered: [buf][row][k] with +8 pad
  // (272B stride -> conflict-free ds_read_b128 A-fragments, 16B aligned).
  __shared__ _Float16 Ah[2][BT][136];
  __shared__ float xs[2][BT];
  __shared__ float predp[2][4][BT];

  const int tid = threadIdx.x;
  const int w = tid >> 6;          // wave 0..3: owns hc [32w, 32w+32)
  const int lane = tid & 63;
  const int col = lane & 15;
  const int quad = lane >> 4;
  const int rowbase = blockIdx.x * BT;

  // zero h state buf0 (h0 = 0)
  {
    unsigned int* a0 = (unsigned int*)&Ah[0][0][0];
    for (int i = tid; i < BT * 136 / 2; i += 256) a0[i] = 0u;
  }
  if (tid < BT) xs[0][tid] = x0[rowbase + tid];  // input for t=0

  // per-lane constants: gate col j = g*128 + w*32 + s*16 + col,
  // pre-scaled by log2e (2*log2e for gate g) to feed exp2 directly.
  float wih_r[4][2], bias_r[4][2];
#pragma unroll
  for (int g = 0; g < 4; ++g) {
    const float sc = (g == 2) ? 2.0f * L2E : L2E;
#pragma unroll
    for (int s = 0; s < 2; ++s) {
      int j = g * 128 + w * 32 + s * 16 + col;
      wih_r[g][s] = Wih[j] * sc;
      bias_r[g][s] = (bih[j] + bhh[j]) * sc;
    }
  }
  float wout_r[2];
  wout_r[0] = Wout[w * 32 + col];
  wout_r[1] = Wout[w * 32 + 16 + col];
  const float bout = boutp[0];

  float c_r[2][4];  // [s][reg] cell state, fp32, in registers
#pragma unroll
  for (int s = 0; s < 2; ++s)
#pragma unroll
    for (int r = 0; r < 4; ++r) c_r[s][r] = 0.f;

  float hn0[4];  // s=0 h_new held until s=1 pairs it for staging
  float pp[4];   // pred partial

  __syncthreads();  // prologue: buf0 + xs[0] ready

#pragma unroll 1
  for (int t = 0; t < SEQ; ++t) {
    const int cur = t & 1, nxt = cur ^ 1;

    // drain pred of t-1 (predp[nxt] complete as of last barrier)
    if (t > 0 && tid < BT) {
      float p = predp[nxt][0][tid] + predp[nxt][1][tid] +
                predp[nxt][2][tid] + predp[nxt][3][tid] + bout;
      out[(size_t)(rowbase + tid) * 7 + (t - 1)] = p;
    }
    // prefetch input for t+1 into the other xs buffer
    if (t + 1 < SEQ && tid < BT) {
      xs[nxt][tid] = x[(size_t)(rowbase + tid) * 7 + t];
    }

#pragma unroll
    for (int s = 0; s < 2; ++s) {
      floatx4 acc[4];  // [g]
#pragma unroll
      for (int g = 0; g < 4; ++g)
        acc[g] = (floatx4){0.f, 0.f, 0.f, 0.f};

#pragma unroll
      for (int kk = 0; kk < 4; ++kk) {
        const int k0 = kk * 32 + quad * 8;
        half8 ah = *(const half8*)&Ah[cur][col][k0];  // A: m = lane&15
#pragma unroll
        for (int g = 0; g < 4; ++g) {
          const int nt = g * 8 + w * 2 + s;
          half8 bhi = *(const half8*)(Bp + ((nt * 4 + kk) * 64 + lane) * 8);
          acc[g] = mfma16(ah, bhi, acc[g]);
        }
      }

#pragma unroll
      for (int r = 0; r < 4; ++r) {
        const int b_loc = quad * 4 + r;  // C row
        const float xv = xs[cur][b_loc];
        // gates pre-scaled: G' = G*log2e (i,f,o) / G*2log2e (g)
        float Gi = acc[0][r] + (xv * wih_r[0][s] + bias_r[0][s]);
        float Gf = acc[1][r] + (xv * wih_r[1][s] + bias_r[1][s]);
        float Gg = acc[2][r] + (xv * wih_r[2][s] + bias_r[2][s]);
        float Go = acc[3][r] + (xv * wih_r[3][s] + bias_r[3][s]);
        // fused-reciprocal cell update (5 exp2 + 2 rcp per element):
        // i*g + f*c = [c(1+A)(1+C) + (1-C)(1+B)] / [(1+A)(1+B)(1+C)]
        float A = exp2f(-Gi);
        float B = exp2f(-Gf);
        float C = exp2f(-Gg);
        float a1 = 1.0f + A, b1 = 1.0f + B, c1 = 1.0f + C;
        float ac = a1 * c1;
        float num = c_r[s][r] * ac + (1.0f - C) * b1;
        float cn = num * __builtin_amdgcn_rcpf(ac * b1);
        c_r[s][r] = cn;
        // h = o * tanh(cn) = (1-E) / [(1+D)(1+E)]
        float D = exp2f(-Go);
        float E = exp2f(cn * (-2.0f * L2E));
        float hn = (1.0f - E) *
                   __builtin_amdgcn_rcpf((1.0f + D) * (1.0f + E));
        if (s == 0) {
          hn0[r] = hn;
          pp[r] = hn * wout_r[0];
        } else {
          pp[r] += hn * wout_r[1];
          // stage h_new (fp16) into the NEXT buffer
          const int hc0 = w * 32 + col;
          Ah[nxt][b_loc][hc0] = (_Float16)hn0[r];
          Ah[nxt][b_loc][hc0 + 16] = (_Float16)hn;
          // reduce pred over the 16 cols this wave holds for this row
          float v = pp[r];
          v += __shfl_xor(v, 1, 64);
          v += __shfl_xor(v, 2, 64);
          v += __shfl_xor(v, 4, 64);
          v += __shfl_xor(v, 8, 64);
          if (col == 0) predp[cur][w][b_loc] = v;
        }
      }
    }
    __syncthreads();  // single barrier: staging, predp, xs prefetch complete
  }

  // drain pred of t=6 (predp[(SEQ-1)&1] = predp[0])
  if (tid < BT) {
    float p = predp[0][0][tid] + predp[0][1][tid] +
              predp[0][2][tid] + predp[0][3][tid] + bout;
    out[(size_t)(rowbase + tid) * 7 + (SEQ - 1)] = p;
  }
}

extern "C" void kernel_launch(void* const* d_in, const int* in_sizes, int n_in,
                              void* d_out, int out_size, void* d_ws, size_t ws_size,
                              hipStream_t stream) {
  const float* x    = (const float*)d_in[0];
  const float* x0   = (const float*)d_in[1];
  const float* Wih  = (const float*)d_in[2];
  const float* Whh  = (const float*)d_in[3];
  const float* bih  = (const float*)d_in[4];
  const float* bhh  = (const float*)d_in[5];
  const float* Wout = (const float*)d_in[6];
  const float* bout = (const float*)d_in[7];
  float* out = (float*)d_out;
  _Float16* Bp = (_Float16*)d_ws;  // 128 KB fragment-major W_hh (fp16)

  pack_kernel<<<256, 256, 0, stream>>>(Whh, Bp);
  lstm_kernel<<<65536 / BT, 256, 0, stream>>>(x, x0, Wih, bih, bhh, Wout, bout,
                                              Bp, out);
}

// Round 10
// 218.919 us; speedup vs baseline: 2.3888x; 2.3888x over previous
//
#include <hip/hip_runtime.h>

// LSTM: HIDDEN=128, SEQ=7, BATCH=65536. fp32 in/out.
// fp16 MFMA GEMM per timestep, c state in registers, h staged via LDS,
// double-buffered, 1 barrier/timestep.
//
// R2-R7: spill fixes, BT=32 dbuf single-barrier, pure-fp16 h, fused-rcp
//        epilogue. Best: 147us (R7, cap 128, ~2-3 waves/SIMD).
// R8: persistent-B -> 1 wave/SIMD, 207us. Throughput ~ resident waves.
// R9: BT=16 @ (256,4): cap=256/N=64 < demand ~160 -> 1.7GB spills, 463us.
//     LAW: launch_bounds(256,N) caps arch VGPR at 256/N.
// R10: BT=16 @ (256,2) (cap 128 = proven spill-free): halved acc/epilogue
//      per wave vs R7 under the same cap -> +1 wave/SIMD headroom.
//      exp2-folded weights kept (bare v_exp, no pre-mul).

#define SEQ 7
#define BT 16
#define L2E 1.442695041f  // log2(e)

typedef _Float16 half8 __attribute__((ext_vector_type(8)));
typedef float floatx4 __attribute__((ext_vector_type(4)));

__device__ __forceinline__ floatx4 mfma16(half8 a, half8 b, floatx4 c) {
  return __builtin_amdgcn_mfma_f32_16x16x32_f16(a, b, c, 0, 0, 0);
}

// Pack W_hh [512][128] fp32 into fragment-major fp16, PRE-SCALED by
// log2e (gates i,f,o) or 2*log2e (gate g) so the epilogue uses bare exp2.
// B-operand layout for mfma_f32_16x16x32_f16: lane = kq*16 + col holds
// B[k = kq*8 + jj][n = col] for the 16-col tile.
__global__ void pack_kernel(const float* __restrict__ Whh,
                            _Float16* __restrict__ Bp) {
  int idx = blockIdx.x * 256 + threadIdx.x;   // 0..65535 = j*128 + k
  int j = idx >> 7, k = idx & 127;
  int g = j >> 7;                             // gate group 0..3 (i,f,g,o)
  float sc = (g == 2) ? 2.0f * L2E : L2E;
  _Float16 hi = (_Float16)(Whh[idx] * sc);
  int nt = j >> 4, col = j & 15;              // 16-col N-tile, col within
  int kk = k >> 5, r = k & 31;                // 32-K step, k within
  int kq = r >> 3, jj = r & 7;
  int base = (((nt << 2) + kk) * 64 + (kq << 4) + col) * 8 + jj;
  Bp[base] = hi;
}

__launch_bounds__(256, 2)
__global__ void lstm_kernel(const float* __restrict__ x,
                            const float* __restrict__ x0,
                            const float* __restrict__ Wih,
                            const float* __restrict__ bih,
                            const float* __restrict__ bhh,
                            const float* __restrict__ Wout,
                            const float* __restrict__ boutp,
                            const _Float16* __restrict__ Bp,
                            float* __restrict__ out) {
  // h staged as fp16, double-buffered: [buf][row][k] with +8 pad
  // (272B stride -> conflict-free ds_read_b128 A-fragments, 16B aligned).
  __shared__ _Float16 Ah[2][BT][136];
  __shared__ float xs[2][BT];
  __shared__ float predp[2][4][BT];

  const int tid = threadIdx.x;
  const int w = tid >> 6;          // wave 0..3: owns hc [32w, 32w+32)
  const int lane = tid & 63;
  const int col = lane & 15;
  const int quad = lane >> 4;
  const int rowbase = blockIdx.x * BT;

  // zero h state buf0 (h0 = 0)
  {
    unsigned int* a0 = (unsigned int*)&Ah[0][0][0];
    for (int i = tid; i < BT * 136 / 2; i += 256) a0[i] = 0u;
  }
  if (tid < BT) xs[0][tid] = x0[rowbase + tid];  // input for t=0

  // per-lane constants: gate col j = g*128 + w*32 + s*16 + col,
  // pre-scaled by log2e (2*log2e for gate g) to feed exp2 directly.
  float wih_r[4][2], bias_r[4][2];
#pragma unroll
  for (int g = 0; g < 4; ++g) {
    const float sc = (g == 2) ? 2.0f * L2E : L2E;
#pragma unroll
    for (int s = 0; s < 2; ++s) {
      int j = g * 128 + w * 32 + s * 16 + col;
      wih_r[g][s] = Wih[j] * sc;
      bias_r[g][s] = (bih[j] + bhh[j]) * sc;
    }
  }
  float wout_r[2];
  wout_r[0] = Wout[w * 32 + col];
  wout_r[1] = Wout[w * 32 + 16 + col];
  const float bout = boutp[0];

  float c_r[2][4];  // [s][reg] cell state, fp32, in registers
#pragma unroll
  for (int s = 0; s < 2; ++s)
#pragma unroll
    for (int r = 0; r < 4; ++r) c_r[s][r] = 0.f;

  float hn0[4];  // s=0 h_new held until s=1 pairs it for staging
  float pp[4];   // pred partial

  __syncthreads();  // prologue: buf0 + xs[0] ready

#pragma unroll 1
  for (int t = 0; t < SEQ; ++t) {
    const int cur = t & 1, nxt = cur ^ 1;

    // drain pred of t-1 (predp[nxt] complete as of last barrier)
    if (t > 0 && tid < BT) {
      float p = predp[nxt][0][tid] + predp[nxt][1][tid] +
                predp[nxt][2][tid] + predp[nxt][3][tid] + bout;
      out[(size_t)(rowbase + tid) * 7 + (t - 1)] = p;
    }
    // prefetch input for t+1 into the other xs buffer
    if (t + 1 < SEQ && tid < BT) {
      xs[nxt][tid] = x[(size_t)(rowbase + tid) * 7 + t];
    }

#pragma unroll
    for (int s = 0; s < 2; ++s) {
      floatx4 acc[4];  // [g]
#pragma unroll
      for (int g = 0; g < 4; ++g)
        acc[g] = (floatx4){0.f, 0.f, 0.f, 0.f};

#pragma unroll
      for (int kk = 0; kk < 4; ++kk) {
        const int k0 = kk * 32 + quad * 8;
        half8 ah = *(const half8*)&Ah[cur][col][k0];  // A: m = lane&15
#pragma unroll
        for (int g = 0; g < 4; ++g) {
          const int nt = g * 8 + w * 2 + s;
          half8 bhi = *(const half8*)(Bp + ((nt * 4 + kk) * 64 + lane) * 8);
          acc[g] = mfma16(ah, bhi, acc[g]);
        }
      }

#pragma unroll
      for (int r = 0; r < 4; ++r) {
        const int b_loc = quad * 4 + r;  // C row
        const float xv = xs[cur][b_loc];
        // gates pre-scaled: G' = G*log2e (i,f,o) / G*2log2e (g)
        float Gi = acc[0][r] + (xv * wih_r[0][s] + bias_r[0][s]);
        float Gf = acc[1][r] + (xv * wih_r[1][s] + bias_r[1][s]);
        float Gg = acc[2][r] + (xv * wih_r[2][s] + bias_r[2][s]);
        float Go = acc[3][r] + (xv * wih_r[3][s] + bias_r[3][s]);
        // fused-reciprocal cell update (5 exp2 + 2 rcp per element):
        // i*g + f*c = [c(1+A)(1+C) + (1-C)(1+B)] / [(1+A)(1+B)(1+C)]
        float A = exp2f(-Gi);
        float B = exp2f(-Gf);
        float C = exp2f(-Gg);
        float a1 = 1.0f + A, b1 = 1.0f + B, c1 = 1.0f + C;
        float ac = a1 * c1;
        float num = c_r[s][r] * ac + (1.0f - C) * b1;
        float cn = num * __builtin_amdgcn_rcpf(ac * b1);
        c_r[s][r] = cn;
        // h = o * tanh(cn) = (1-E) / [(1+D)(1+E)]
        float D = exp2f(-Go);
        float E = exp2f(cn * (-2.0f * L2E));
        float hn = (1.0f - E) *
                   __builtin_amdgcn_rcpf((1.0f + D) * (1.0f + E));
        if (s == 0) {
          hn0[r] = hn;
          pp[r] = hn * wout_r[0];
        } else {
          pp[r] += hn * wout_r[1];
          // stage h_new (fp16) into the NEXT buffer
          const int hc0 = w * 32 + col;
          Ah[nxt][b_loc][hc0] = (_Float16)hn0[r];
          Ah[nxt][b_loc][hc0 + 16] = (_Float16)hn;
          // reduce pred over the 16 cols this wave holds for this row
          float v = pp[r];
          v += __shfl_xor(v, 1, 64);
          v += __shfl_xor(v, 2, 64);
          v += __shfl_xor(v, 4, 64);
          v += __shfl_xor(v, 8, 64);
          if (col == 0) predp[cur][w][b_loc] = v;
        }
      }
    }
    __syncthreads();  // single barrier: staging, predp, xs prefetch complete
  }

  // drain pred of t=6 (predp[(SEQ-1)&1] = predp[0])
  if (tid < BT) {
    float p = predp[0][0][tid] + predp[0][1][tid] +
              predp[0][2][tid] + predp[0][3][tid] + bout;
    out[(size_t)(rowbase + tid) * 7 + (SEQ - 1)] = p;
  }
}

extern "C" void kernel_launch(void* const* d_in, const int* in_sizes, int n_in,
                              void* d_out, int out_size, void* d_ws, size_t ws_size,
                              hipStream_t stream) {
  const float* x    = (const float*)d_in[0];
  const float* x0   = (const float*)d_in[1];
  const float* Wih  = (const float*)d_in[2];
  const float* Whh  = (const float*)d_in[3];
  const float* bih  = (const float*)d_in[4];
  const float* bhh  = (const float*)d_in[5];
  const float* Wout = (const float*)d_in[6];
  const float* bout = (const float*)d_in[7];
  float* out = (float*)d_out;
  _Float16* Bp = (_Float16*)d_ws;  // 128 KB fragment-major W_hh (fp16)

  pack_kernel<<<256, 256, 0, stream>>>(Whh, Bp);
  lstm_kernel<<<65536 / BT, 256, 0, stream>>>(x, x0, Wih, bih, bhh, Wout, bout,
                                              Bp, out);
}